// Round 15
// baseline (82.846 us; speedup 1.0000x reference)
//
#include <hip/hip_runtime.h>

// Diversity5: out = mean_b( SCALE * sum_{i<j} corr(v_i[b], v_j[b]) ),
// v_m = normalize(center(softmax(outputs_m / T))).
//
// One-pass reformulation (R4): with u = exp(x/T) - 1,
//   A_m = sum_c u_m,  B_ij = sum_c u_i u_j  (i<=j, 15 pairs)
//   corr_ij = (C*B_ij - A_i*A_j) * rsqrt(C*B_ii - A_i^2) * rsqrt(C*B_jj - A_j^2)
// R9/R11 (proven, absmax 0, 61.9us): persistent waves; inline-asm
//   global_load_dwordx4 + counted vmcnt + sched_barrier(0) (rule #18);
//   block partials; per-block phase stagger.
// R7/R8/R10/R12 lessons (4 failures): asm-load dests in flight ACROSS a
//   reduction get spilled/PHI-copied -> corruption. SAFE INVARIANT (R9):
//   every asm dest is issued AND consumed in straight-line code before any
//   register-hungry region runs.
// R15: 2-ROW BURST within that invariant. Issue 40 loads (rows A+B),
//   consume 8 slots behind vmcnt(35..0), THEN do both rows' reductions
//   (40 interleaved butterfly chains + 2 epilogues). One drain+reduce
//   bubble per 2 rows instead of per row; row-B waits are pre-aged by
//   row-A's consume time. Peak ~216 VGPR < 512 cap (launch_bounds(256,1)).

typedef float f32x4 __attribute__((ext_vector_type(4)));

#define CDIM   1000
#define C4DIM  250
#define NM     5
#define NP     15
#define ROWS   4            // rows per wave (2 bursts of 2)
#define T_INV  (1.0f / 20.0f)
#define SCALEF 0.3f

#define GLOAD(dst, p) \
    asm volatile("global_load_dwordx4 %0, %1, off" : "=v"(dst) : "v"(p) : "memory")

#define WAITVM(N)                                              \
    asm volatile("s_waitcnt vmcnt(" #N ")" ::: "memory");      \
    __builtin_amdgcn_sched_barrier(0)

// Issue one row's 20 loads, slot-major (vmcnt retire order = consume order).
__device__ __forceinline__ void issue_row(const float* const* rp, size_t ro,
                                          int lane, int i3,
                                          f32x4* x0, f32x4* x1, f32x4* x2, f32x4* x3)
{
    #pragma unroll
    for (int m = 0; m < NM; ++m) GLOAD(x0[m], rp[m] + ro + (size_t)lane * 4);
    #pragma unroll
    for (int m = 0; m < NM; ++m) GLOAD(x1[m], rp[m] + ro + (size_t)(lane + 64) * 4);
    #pragma unroll
    for (int m = 0; m < NM; ++m) GLOAD(x2[m], rp[m] + ro + (size_t)(lane + 128) * 4);
    #pragma unroll
    for (int m = 0; m < NM; ++m) GLOAD(x3[m], rp[m] + ro + (size_t)i3 * 4);
}

template <bool MASKED>
__device__ __forceinline__ void slot_accum(const f32x4* xs, bool act,
                                           float* A, float* Bv)
{
    float u[NM][4];
    #pragma unroll
    for (int m = 0; m < NM; ++m) {
        #pragma unroll
        for (int c = 0; c < 4; ++c) {
            float xv = xs[m][c];
            if (MASKED) xv = act ? xv : 0.0f;   // exp(0)-1 == 0 exactly
            u[m][c] = __expf(xv * T_INV) - 1.0f;
        }
    }
    #pragma unroll
    for (int c = 0; c < 4; ++c) {
        #pragma unroll
        for (int i = 0; i < NM; ++i) A[i] += u[i][c];
        int p = 0;
        #pragma unroll
        for (int i = 0; i < NM; ++i) {
            #pragma unroll
            for (int j = i; j < NM; ++j) {
                Bv[p] = fmaf(u[i][c], u[j][c], Bv[p]);
                ++p;
            }
        }
    }
}

// fp32 epilogue for one row's reduced A/Bv -> SCALE * sum_{i<j} corr_ij
__device__ __forceinline__ float epilogue(const float* A, const float* Bv)
{
    const float Cf = (float)CDIM;
    const int diag[NM] = {0, 5, 9, 12, 14};
    float rden[NM];
    #pragma unroll
    for (int i = 0; i < NM; ++i)
        rden[i] = rsqrtf(fmaf(Cf, Bv[diag[i]], -A[i] * A[i]));

    float d = 0.0f;
    int p = 0;
    #pragma unroll
    for (int i = 0; i < NM; ++i) {
        #pragma unroll
        for (int j = i; j < NM; ++j) {
            if (j > i)
                d += fmaf(Cf, Bv[p], -A[i] * A[j]) * rden[i] * rden[j];
            ++p;
        }
    }
    return SCALEF * d;
}

__global__ __launch_bounds__(256, 1) void diversity_rows(
    const float* __restrict__ o1, const float* __restrict__ o2,
    const float* __restrict__ o3, const float* __restrict__ o4,
    const float* __restrict__ o5, float* __restrict__ ws, int B)
{
    const int lane = threadIdx.x & 63;
    const int wid  = threadIdx.x >> 6;
    const int b0   = (blockIdx.x * 4 + wid) * ROWS;   // first row of this wave

    __shared__ float sm4[4];

    // One-time per-block phase stagger (R11 exact): de-correlate co-resident
    // blocks' drain+reduce phases. s_sleep is timing-only.
    {
        const int stag = (blockIdx.x >> 8) & 3;
        for (int i = 0; i < stag; ++i)
            __builtin_amdgcn_s_sleep(4);     // 4*64 = 256 cycles each
    }

    const bool act3 = (lane + 192) < C4DIM;              // 250 float4/row
    const int  i3   = act3 ? (lane + 192) : (C4DIM - 1); // clamp: never OOB

    float dsum = 0.0f;

    if (b0 < B) {
        const float* rp[NM] = {
            o1 + (size_t)b0 * CDIM, o2 + (size_t)b0 * CDIM, o3 + (size_t)b0 * CDIM,
            o4 + (size_t)b0 * CDIM, o5 + (size_t)b0 * CDIM};

        #pragma unroll 1
        for (int burst = 0; burst < ROWS / 2; ++burst) {
            // ---- issue BOTH rows' 40 loads (rows A and B) ----
            f32x4 xa0[NM], xa1[NM], xa2[NM], xa3[NM];
            f32x4 xb0[NM], xb1[NM], xb2[NM], xb3[NM];
            issue_row(rp, 0,            lane, i3, xa0, xa1, xa2, xa3);
            issue_row(rp, (size_t)CDIM, lane, i3, xb0, xb1, xb2, xb3);

            float A2[2][NM], Bv2[2][NP];
            #pragma unroll
            for (int r = 0; r < 2; ++r) {
                #pragma unroll
                for (int i = 0; i < NM; ++i) A2[r][i] = 0.0f;
                #pragma unroll
                for (int p = 0; p < NP; ++p) Bv2[r][p] = 0.0f;
            }

            // ---- consume 8 slots behind counted vmcnt (40 outstanding) ----
            WAITVM(35);  slot_accum<false>(xa0, true, A2[0], Bv2[0]);
            WAITVM(30);  slot_accum<false>(xa1, true, A2[0], Bv2[0]);
            WAITVM(25);  slot_accum<false>(xa2, true, A2[0], Bv2[0]);
            WAITVM(20);  slot_accum<true >(xa3, act3, A2[0], Bv2[0]);
            WAITVM(15);  slot_accum<false>(xb0, true, A2[1], Bv2[1]);
            WAITVM(10);  slot_accum<false>(xb1, true, A2[1], Bv2[1]);
            WAITVM(5);   slot_accum<false>(xb2, true, A2[1], Bv2[1]);
            WAITVM(0);   slot_accum<true >(xb3, act3, A2[1], Bv2[1]);
            __builtin_amdgcn_sched_barrier(0);
            // all asm-load state now dead (safe invariant, R9)

            // ---- butterfly: 40 interleaved chains, 6 steps ----
            #pragma unroll
            for (int off = 32; off >= 1; off >>= 1) {
                #pragma unroll
                for (int r = 0; r < 2; ++r) {
                    #pragma unroll
                    for (int i = 0; i < NM; ++i)
                        A2[r][i] += __shfl_xor(A2[r][i], off);
                    #pragma unroll
                    for (int p = 0; p < NP; ++p)
                        Bv2[r][p] += __shfl_xor(Bv2[r][p], off);
                }
            }

            // ---- two epilogues ----
            dsum += epilogue(A2[0], Bv2[0]);
            dsum += epilogue(A2[1], Bv2[1]);

            #pragma unroll
            for (int m = 0; m < NM; ++m) rp[m] += 2 * CDIM;
        }
    }

    // per-block partial (fixed order): 4 waves -> 1 float
    if (lane == 0) sm4[wid] = dsum;
    __syncthreads();
    if (threadIdx.x == 0)
        ws[blockIdx.x] = (sm4[0] + sm4[1]) + (sm4[2] + sm4[3]);
}

// Deterministic fixed-order reduction of nblk block partials -> mean over B.
__global__ __launch_bounds__(256) void final_reduce(
    const float* __restrict__ ws, float* __restrict__ out, int nblk, int B)
{
    __shared__ double sm[256];
    double acc = 0.0;
    for (int i = threadIdx.x; i < nblk; i += 256)
        acc += (double)ws[i];
    sm[threadIdx.x] = acc;
    __syncthreads();
    #pragma unroll
    for (int s = 128; s > 0; s >>= 1) {
        if (threadIdx.x < s) sm[threadIdx.x] += sm[threadIdx.x + s];
        __syncthreads();
    }
    if (threadIdx.x == 0)
        out[0] = (float)(sm[0] / (double)B);
}

extern "C" void kernel_launch(void* const* d_in, const int* in_sizes, int n_in,
                              void* d_out, int out_size, void* d_ws, size_t ws_size,
                              hipStream_t stream)
{
    const float* o1 = (const float*)d_in[0];
    const float* o2 = (const float*)d_in[1];
    const float* o3 = (const float*)d_in[2];
    const float* o4 = (const float*)d_in[3];
    const float* o5 = (const float*)d_in[4];
    // d_in[5] (targets) unused by the reference.

    float* ws  = (float*)d_ws;
    float* out = (float*)d_out;

    const int B = in_sizes[0] / CDIM;                 // 16384
    const int waves  = (B + ROWS - 1) / ROWS;         // 4096
    const int blocks = (waves + 3) / 4;               // 1024

    diversity_rows<<<blocks, 256, 0, stream>>>(o1, o2, o3, o4, o5, ws, B);
    final_reduce<<<1, 256, 0, stream>>>(ws, out, blocks, B);
}

// Round 16
// 62.850 us; speedup vs baseline: 1.3182x; 1.3182x over previous
//
#include <hip/hip_runtime.h>

// Diversity5: out = mean_b( SCALE * sum_{i<j} corr(v_i[b], v_j[b]) ),
// v_m = normalize(center(softmax(outputs_m / T))).
//
// FINAL (R11, proven 61.9us, absmax 0.0):
// One-pass reformulation: with u = exp(x/T) - 1,
//   A_m = sum_c u_m,  B_ij = sum_c u_i u_j  (i<=j, 15 pairs)
//   corr_ij = (C*B_ij - A_i*A_j) * rsqrt(C*B_ii - A_i^2) * rsqrt(C*B_jj - A_j^2)
// (softmax mean is exactly 1/C; pair-sum via per-pair correlations; the
//  C(C+A_i)(C+A_j) denominators cancel between numerator and norms.)
//
// Structure: persistent waves, 4 rows each, ONE-SHOT per row: 20 inline-asm
// global_load_dwordx4 (slot-major) -> counted s_waitcnt vmcnt(15/10/5/0) +
// sched_barrier(0) (rule #18) -> 20-chain interleaved butterfly -> fp32
// epilogue. Per-block partial sums; one-time per-block s_sleep stagger to
// de-correlate drain phases. ~89% of the 6.3 TB/s blended HBM+L3 ceiling.
//
// Negative results (kept for the record):
//  - R7/R8/R10/R12: cross-row in-flight asm-load dests (any form: spilled,
//    loop-carried PHI, straight-line high-pressure) get corrupted by the
//    register allocator -> NaN/stale/aperture-fault. Unreachable from HIP.
//  - R15: 2-row burst @ launch_bounds(256,1) -> occupancy 28%->11%, 83us.
//    4 waves/CU x 40-deep loses to 8+ waves/CU x 20-deep (TLP > ILP here).
//  - R3/R4: block-per-row with LDS barriers -> 86us (barrier coupling).

typedef float f32x4 __attribute__((ext_vector_type(4)));

#define CDIM   1000
#define C4DIM  250
#define NM     5
#define NP     15
#define ROWS   4
#define T_INV  (1.0f / 20.0f)
#define SCALEF 0.3f

#define GLOAD(dst, p) \
    asm volatile("global_load_dwordx4 %0, %1, off" : "=v"(dst) : "v"(p) : "memory")

#define WAITVM(N)                                              \
    asm volatile("s_waitcnt vmcnt(" #N ")" ::: "memory");      \
    __builtin_amdgcn_sched_barrier(0)

// Issue one row's 20 loads in slot-major order (vmcnt retire order must
// match consumption order: all x0s, then x1s, x2s, x3s).
__device__ __forceinline__ void issue_row(const float* const* rp, int lane, int i3,
                                          f32x4* x0, f32x4* x1, f32x4* x2, f32x4* x3)
{
    #pragma unroll
    for (int m = 0; m < NM; ++m) GLOAD(x0[m], rp[m] + (size_t)lane * 4);
    #pragma unroll
    for (int m = 0; m < NM; ++m) GLOAD(x1[m], rp[m] + (size_t)(lane + 64) * 4);
    #pragma unroll
    for (int m = 0; m < NM; ++m) GLOAD(x2[m], rp[m] + (size_t)(lane + 128) * 4);
    #pragma unroll
    for (int m = 0; m < NM; ++m) GLOAD(x3[m], rp[m] + (size_t)i3 * 4);
}

template <bool MASKED>
__device__ __forceinline__ void slot_accum(const f32x4* xs, bool act,
                                           float* A, float* Bv)
{
    float u[NM][4];
    #pragma unroll
    for (int m = 0; m < NM; ++m) {
        #pragma unroll
        for (int c = 0; c < 4; ++c) {
            float xv = xs[m][c];
            if (MASKED) xv = act ? xv : 0.0f;   // exp(0)-1 == 0 exactly
            u[m][c] = __expf(xv * T_INV) - 1.0f;
        }
    }
    #pragma unroll
    for (int c = 0; c < 4; ++c) {
        #pragma unroll
        for (int i = 0; i < NM; ++i) A[i] += u[i][c];
        int p = 0;
        #pragma unroll
        for (int i = 0; i < NM; ++i) {
            #pragma unroll
            for (int j = i; j < NM; ++j) {
                Bv[p] = fmaf(u[i][c], u[j][c], Bv[p]);
                ++p;
            }
        }
    }
}

__global__ __launch_bounds__(256) void diversity_rows(
    const float* __restrict__ o1, const float* __restrict__ o2,
    const float* __restrict__ o3, const float* __restrict__ o4,
    const float* __restrict__ o5, float* __restrict__ ws, int B)
{
    const int lane = threadIdx.x & 63;
    const int wid  = threadIdx.x >> 6;
    const int b0   = (blockIdx.x * 4 + wid) * ROWS;   // first row of this wave

    __shared__ float sm4[4];

    // One-time phase stagger: co-resident blocks (blockIdx differing by 256
    // with 1024 blocks on 256 CUs) get 0/256/512/768-cycle offsets so their
    // per-row drain+reduce phases don't align. Timing-only, no correctness
    // surface.
    {
        const int stag = (blockIdx.x >> 8) & 3;
        for (int i = 0; i < stag; ++i)
            __builtin_amdgcn_s_sleep(4);     // 4*64 = 256 cycles each
    }

    const bool act3 = (lane + 192) < C4DIM;              // 250 float4/row
    const int  i3   = act3 ? (lane + 192) : (C4DIM - 1); // clamp: never OOB

    float dsum = 0.0f;

    if (b0 < B) {
        const float* rp[NM] = {
            o1 + (size_t)b0 * CDIM, o2 + (size_t)b0 * CDIM, o3 + (size_t)b0 * CDIM,
            o4 + (size_t)b0 * CDIM, o5 + (size_t)b0 * CDIM};

        #pragma unroll 1
        for (int r = 0; r < ROWS; ++r) {
            f32x4 x0[NM], x1[NM], x2[NM], x3[NM];
            issue_row(rp, lane, i3, x0, x1, x2, x3);

            float A[NM], Bv[NP];
            #pragma unroll
            for (int i = 0; i < NM; ++i) A[i] = 0.0f;
            #pragma unroll
            for (int p = 0; p < NP; ++p) Bv[p] = 0.0f;

            // consume behind counted vmcnt (20 outstanding after issue)
            WAITVM(15);  slot_accum<false>(x0, true, A, Bv);
            WAITVM(10);  slot_accum<false>(x1, true, A, Bv);
            WAITVM(5);   slot_accum<false>(x2, true, A, Bv);
            WAITVM(0);   slot_accum<true >(x3, act3, A, Bv);
            __builtin_amdgcn_sched_barrier(0);

            // butterfly: 20 interleaved chains, 6 steps (asm state all dead)
            #pragma unroll
            for (int off = 32; off >= 1; off >>= 1) {
                #pragma unroll
                for (int i = 0; i < NM; ++i) A[i] += __shfl_xor(A[i], off);
                #pragma unroll
                for (int p = 0; p < NP; ++p) Bv[p] += __shfl_xor(Bv[p], off);
            }

            // d = sum_{i<j} corr_ij, fp32 epilogue (all lanes redundantly)
            {
                const float Cf = (float)CDIM;
                const int diag[NM] = {0, 5, 9, 12, 14};
                float rden[NM];
                #pragma unroll
                for (int i = 0; i < NM; ++i)
                    rden[i] = rsqrtf(fmaf(Cf, Bv[diag[i]], -A[i] * A[i]));

                float d = 0.0f;
                int p = 0;
                #pragma unroll
                for (int i = 0; i < NM; ++i) {
                    #pragma unroll
                    for (int j = i; j < NM; ++j) {
                        if (j > i)
                            d += fmaf(Cf, Bv[p], -A[i] * A[j]) * rden[i] * rden[j];
                        ++p;
                    }
                }
                dsum += SCALEF * d;
            }

            #pragma unroll
            for (int m = 0; m < NM; ++m) rp[m] += CDIM;
        }
    }

    // per-block partial (fixed order): 4 waves -> 1 float
    if (lane == 0) sm4[wid] = dsum;
    __syncthreads();
    if (threadIdx.x == 0)
        ws[blockIdx.x] = (sm4[0] + sm4[1]) + (sm4[2] + sm4[3]);
}

// Deterministic fixed-order reduction of nblk block partials -> mean over B.
__global__ __launch_bounds__(256) void final_reduce(
    const float* __restrict__ ws, float* __restrict__ out, int nblk, int B)
{
    __shared__ double sm[256];
    double acc = 0.0;
    for (int i = threadIdx.x; i < nblk; i += 256)
        acc += (double)ws[i];
    sm[threadIdx.x] = acc;
    __syncthreads();
    #pragma unroll
    for (int s = 128; s > 0; s >>= 1) {
        if (threadIdx.x < s) sm[threadIdx.x] += sm[threadIdx.x + s];
        __syncthreads();
    }
    if (threadIdx.x == 0)
        out[0] = (float)(sm[0] / (double)B);
}

extern "C" void kernel_launch(void* const* d_in, const int* in_sizes, int n_in,
                              void* d_out, int out_size, void* d_ws, size_t ws_size,
                              hipStream_t stream)
{
    const float* o1 = (const float*)d_in[0];
    const float* o2 = (const float*)d_in[1];
    const float* o3 = (const float*)d_in[2];
    const float* o4 = (const float*)d_in[3];
    const float* o5 = (const float*)d_in[4];
    // d_in[5] (targets) unused by the reference.

    float* ws  = (float*)d_ws;
    float* out = (float*)d_out;

    const int B = in_sizes[0] / CDIM;                 // 16384
    const int waves  = (B + ROWS - 1) / ROWS;         // 4096
    const int blocks = (waves + 3) / 4;               // 1024

    diversity_rows<<<blocks, 256, 0, stream>>>(o1, o2, o3, o4, o5, ws, B);
    final_reduce<<<1, 256, 0, stream>>>(ws, out, blocks, B);
}